// Round 17
// baseline (277.212 us; speedup 1.0000x reference)
//
#include <hip/hip_runtime.h>
#include <hip/hip_fp16.h>
#include <math.h>

#define NNODES 40000
#define NEDGES 640000
#define NGRAPH 64
#define CAP 96                 // slots per dst bucket (max random-degree ~45)
constexpr float LN_EPS = 1e-5f;

// ================= software fp8 (e4m3, bias 7, FTZ<2^-6, round-half-up) =============
// encode: float -> 8-bit code (cold path, gemm epilogue)
__device__ __forceinline__ unsigned fp8_enc(float v) {
    unsigned hb = (unsigned)__half_as_ushort(__float2half_rn(v));
    unsigned sign = (hb >> 8) & 0x80u;
    unsigned mag = hb & 0x7fffu;
    if (mag < 0x2400u) return sign;               // flush |v| < 2^-6 to signed zero-code
    unsigned r = (mag - 0x2000u + 0x40u) >> 7;    // rebias to 4-bit exp + round
    return sign | (r > 0x7fu ? 0x7fu : r);
}
// decode a PAIR (2 fp8 in a ushort) -> float2, 5 packed-u32 ops + 2 cvt (hot path)
__device__ __forceinline__ float2 fp8_dec2(unsigned u) {
    unsigned t = (u | (u << 8)) & 0x00ff00ffu;     // bytes into 16-bit slots
    unsigned f = ((t & 0x00800080u) << 8) |        // sign -> bit 15 of each half
                 (((t & 0x007f007fu) << 7) + 0x20002000u);  // mag -> fp16, rebias +8
    return __half22float2(__builtin_bit_cast(__half2, f));
}

// ================= butterfly wave reduction (all lanes get result) =================
__device__ __forceinline__ float bf_sum(float v) {
    #pragma unroll
    for (int o = 32; o > 0; o >>= 1) v += __shfl_xor(v, o);
    return v;
}

// ================= prep: zero cnt/sums + transpose W1,W2 (one kernel) =================
__global__ void prep(const float* __restrict__ W1, const float* __restrict__ W2,
                     float* __restrict__ Wt1, float* __restrict__ Wt2,
                     int* __restrict__ cnt, float* __restrict__ sums) {
    int t = blockIdx.x * 256 + threadIdx.x;
    if (t < NNODES) cnt[t] = 0;
    if (t < 128 * 128) { int o = t / 128, i = t % 128; Wt1[i * 128 + o] = W1[t]; }
    if (t < 64 * 128)  { int o = t / 128, i = t % 128; Wt2[i * 64 + o] = W2[t]; }
    if (t < NGRAPH * 64) sums[t] = 0.f;
}

// ================= binning (random edges only; self-loops analytic) =================
__global__ void bin_edges(const int* __restrict__ ei, int E,
                          int* __restrict__ cnt, unsigned short* __restrict__ ssrc) {
    int e = blockIdx.x * blockDim.x + threadIdx.x;
    if (e >= E) return;
    int s = ei[e], d = ei[E + e];
    int pos = atomicAdd(cnt + d, 1);
    if (pos < CAP) ssrc[d * CAP + pos] = (unsigned short)s;
}

// ================= GEMM + scores: register-tiled; H out fp8(layer1) / fp16 =========
template<int DIN, int DOUT, int NPT, int FP8>
__global__ __launch_bounds__(256) void gemm_scores(
        const float* __restrict__ X, const float* __restrict__ Wt,
        const float* __restrict__ asrc, const float* __restrict__ adst,
        void* __restrict__ Hout, float* __restrict__ S, float* __restrict__ Dv) {
    constexpr int CHG = DOUT / 4;        // threads along channel dim
    constexpr int NG  = 256 / CHG;       // node-groups per block
    constexpr int NPB = NG * NPT;        // nodes per block
    static_assert(NPB == 64, "NPB must be 64");
    __shared__ float xs[DIN][NPB];
    __shared__ float ps[NG][NPT][2];
    const int base = blockIdx.x * NPB;
    const int tid = threadIdx.x;
    #pragma unroll
    for (int i4 = tid; i4 < NPB * DIN / 4; i4 += 256) {
        const int nd = i4 % NPB, c4 = i4 / NPB;
        float4 v = *(const float4*)(X + (size_t)(base + nd) * DIN + 4 * c4);
        xs[4 * c4 + 0][nd] = v.x;
        xs[4 * c4 + 1][nd] = v.y;
        xs[4 * c4 + 2][nd] = v.z;
        xs[4 * c4 + 3][nd] = v.w;
    }
    __syncthreads();
    const int cg = tid % CHG, ng = tid / CHG;
    const int c0 = 4 * cg, n0 = ng * NPT;
    float acc[NPT][4];
    #pragma unroll
    for (int n = 0; n < NPT; ++n)
        #pragma unroll
        for (int k = 0; k < 4; ++k) acc[n][k] = 0.f;
    #pragma unroll 2
    for (int i = 0; i < DIN; ++i) {
        const float4 w = *(const float4*)(Wt + i * DOUT + c0);
        #pragma unroll
        for (int n4 = 0; n4 < NPT / 4; ++n4) {
            const float4 xv = *(const float4*)&xs[i][n0 + 4 * n4];
            const float xf[4] = {xv.x, xv.y, xv.z, xv.w};
            #pragma unroll
            for (int j = 0; j < 4; ++j) {
                const int n = 4 * n4 + j;
                acc[n][0] += xf[j] * w.x; acc[n][1] += xf[j] * w.y;
                acc[n][2] += xf[j] * w.z; acc[n][3] += xf[j] * w.w;
            }
        }
    }
    #pragma unroll
    for (int n = 0; n < NPT; ++n) {
        const size_t node = (size_t)(base + n0 + n);
        if (FP8) {
            unsigned p = fp8_enc(acc[n][0]) | (fp8_enc(acc[n][1]) << 8) |
                         (fp8_enc(acc[n][2]) << 16) | (fp8_enc(acc[n][3]) << 24);
            *(unsigned*)((unsigned char*)Hout + node * DOUT + c0) = p;
        } else {
            __half2 p01 = __floats2half2_rn(acc[n][0], acc[n][1]);
            __half2 p23 = __floats2half2_rn(acc[n][2], acc[n][3]);
            __half2* hp = (__half2*)((__half*)Hout + node * DOUT + c0);
            hp[0] = p01; hp[1] = p23;
        }
    }
    const float4 asf = *(const float4*)(asrc + c0);
    const float4 adf = *(const float4*)(adst + c0);
    float sp[NPT], dp[NPT];
    #pragma unroll
    for (int n = 0; n < NPT; ++n) {
        sp[n] = acc[n][0]*asf.x + acc[n][1]*asf.y + acc[n][2]*asf.z + acc[n][3]*asf.w;
        dp[n] = acc[n][0]*adf.x + acc[n][1]*adf.y + acc[n][2]*adf.z + acc[n][3]*adf.w;
    }
    #pragma unroll
    for (int o = CHG / 2; o > 0; o >>= 1) {
        #pragma unroll
        for (int n = 0; n < NPT; ++n) {
            sp[n] += __shfl_xor(sp[n], o);
            dp[n] += __shfl_xor(dp[n], o);
        }
    }
    if (cg == 0) {
        #pragma unroll
        for (int n = 0; n < NPT; ++n) { ps[ng][n][0] = sp[n]; ps[ng][n][1] = dp[n]; }
    }
    __syncthreads();
    if (tid < NPB) {
        S[base + tid]  = ps[tid / NPT][tid % NPT][0];
        Dv[base + tid] = ps[tid / NPT][tid % NPT][1];
    }
}

// ---- per-edge row loaders ----
template<int D, int FP8>
__device__ __forceinline__ void row_ld(const void* H, int sj, int lane,
                                       float& h0, float& h1) {
    if (D == 64) {           // fp16, 1 half per lane
        h0 = __half2float(((const __half*)H)[(size_t)sj * 64 + lane]);
        h1 = 0.f;
    } else if (FP8) {        // fp8 x2 per lane (channels 2l, 2l+1); row = 128 B = 1 line
        unsigned short r = *(const unsigned short*)
            ((const unsigned char*)H + (size_t)sj * 128 + 2 * lane);
        float2 f = fp8_dec2((unsigned)r);
        h0 = f.x; h1 = f.y;
    } else {                 // fp16 x2 per lane
        const float2 f = __half22float2(
            *(const __half2*)((const __half*)H + (size_t)sj * 128 + 2 * lane));
        h0 = f.x; h1 = f.y;
    }
}

// ================= fused GAT: 1 node/wave, unroll 8, two-readlane hot loop ==========
template<int D, int POOL, int FP8>
__global__ __launch_bounds__(256) void gat_aggr(
        const int* __restrict__ cnt, const unsigned short* __restrict__ ssrc,
        const float* __restrict__ S, const float* __restrict__ Dv,
        const void* __restrict__ H,
        const float* __restrict__ b, const float* __restrict__ gam,
        const float* __restrict__ bet,
        float* __restrict__ out, const int* __restrict__ batch,
        float* __restrict__ sums) {
    constexpr int VPL = D / 64;
    const int lane = threadIdx.x & 63;
    const int node = blockIdx.x * 4 + (threadIdx.x >> 6);   // 1 node per wave
    const int deg = min(__builtin_amdgcn_readfirstlane(cnt[node]), CAP);
    const float dsc = Dv[node];
    float ts = S[node] + dsc;
    ts = ts > 0.f ? ts : 0.2f * ts;
    const float aself = __expf(ts);                 // analytic self-loop term

    float z, acc0 = 0.f, acc1 = 0.f;

    if (deg <= 64) {
        int s = 0; float a = 0.f;
        if (lane < deg) {
            s = ssrc[node * CAP + lane];
            float t = S[s] + dsc;
            t = t > 0.f ? t : 0.2f * t;
            a = __expf(t);
        }
        z = bf_sum(a);
        const int ab = __float_as_int(a);
        const int nmax = (deg + 7) & ~7;            // <= 64
        for (int j = 0; j < nmax; j += 8) {
            float af[8], h0[8], h1[8];
            #pragma unroll
            for (int u = 0; u < 8; ++u) {
                const int sj = __builtin_amdgcn_readlane(s, j + u);
                af[u] = __int_as_float(__builtin_amdgcn_readlane(ab, j + u));
                row_ld<D, FP8>(H, sj, lane, h0[u], h1[u]);
            }
            #pragma unroll
            for (int u = 0; u < 8; ++u) {
                acc0 += af[u] * h0[u];
                if (VPL == 2) acc1 += af[u] * h1[u];
            }
        }
    } else {
        float zz = 0.f;
        const int r0 = node * CAP;
        for (int bse = 0; bse < deg; bse += 64) {
            const int n = min(64, deg - bse);
            int s = 0; float a = 0.f;
            if (lane < n) {
                s = ssrc[r0 + bse + lane];
                float t = S[s] + dsc;
                t = t > 0.f ? t : 0.2f * t;
                a = __expf(t);
            }
            zz += bf_sum(a);
            const int abits = __float_as_int(a);
            for (int j = 0; j < n; ++j) {
                const int sj = __builtin_amdgcn_readlane(s, j);
                const float aj = __int_as_float(__builtin_amdgcn_readlane(abits, j));
                float h0, h1;
                row_ld<D, FP8>(H, sj, lane, h0, h1);
                acc0 += aj * h0;
                if (VPL == 2) acc1 += aj * h1;
            }
        }
        z = zz;
    }

    // ---- self-loop contribution (coalesced row load) + z completion ----
    {
        float h0, h1;
        row_ld<D, FP8>(H, node, lane, h0, h1);
        acc0 += aself * h0;
        if (VPL == 2) acc1 += aself * h1;
        z += aself;
    }

    // ---- normalize + bias + ReLU + LayerNorm, intra-wave ----
    const float zinv = 1.0f / z;
    float vv[VPL], lsum = 0.f;
    vv[0] = acc0;
    if (VPL == 2) vv[1] = acc1;
    #pragma unroll
    for (int k = 0; k < VPL; ++k) {
        const int ch = VPL * lane + k;
        vv[k] = fmaxf(vv[k] * zinv + b[ch], 0.f);
        lsum += vv[k];
    }
    const float mu = bf_sum(lsum) / D;
    float q = 0.f;
    #pragma unroll
    for (int k = 0; k < VPL; ++k) { vv[k] -= mu; q += vv[k] * vv[k]; }
    const float rstd = rsqrtf(bf_sum(q) / D + LN_EPS);
    #pragma unroll
    for (int k = 0; k < VPL; ++k) {
        const int ch = VPL * lane + k;
        vv[k] = gam[ch] * vv[k] * rstd + bet[ch];
    }
    if (POOL) {
        const int bg = batch[node];                 // uniform per wave
        atomicAdd(&sums[bg * D + lane], vv[0]);     // POOL only used with D=64
    } else {
        if (VPL == 1) out[(size_t)node * D + lane] = vv[0];
        else *(float2*)(out + (size_t)node * D + 2 * lane) = make_float2(vv[0], vv[1]);
    }
}

// ================= head: mean (cnt via binary search on sorted batch) + 2 linears ====
__global__ void final_head(const float* __restrict__ sums, const int* __restrict__ batch,
                           const float* __restrict__ Wl, const float* __restrict__ bl,
                           const float* __restrict__ Wc, const float* __restrict__ bc,
                           float* __restrict__ out) {
    __shared__ float p[64];
    __shared__ float red[64];
    const int g = blockIdx.x, tid = threadIdx.x;
    int lo = 0, hi = NNODES;
    while (lo < hi) { int mid = (lo + hi) >> 1; if (batch[mid] < g) lo = mid + 1; else hi = mid; }
    int lo2 = lo, hi2 = NNODES;
    while (lo2 < hi2) { int mid = (lo2 + hi2) >> 1; if (batch[mid] < g + 1) lo2 = mid + 1; else hi2 = mid; }
    const float cnt = (float)(lo2 - lo);
    p[tid] = sums[g * 64 + tid] / fmaxf(cnt, 1.0f);
    __syncthreads();
    float t = bl[tid];
    #pragma unroll 8
    for (int k = 0; k < 64; ++k) t += Wl[tid * 64 + k] * p[k];
    red[tid] = Wc[tid] * t;
    __syncthreads();
    for (int s = 32; s > 0; s >>= 1) {
        if (tid < s) red[tid] += red[tid + s];
        __syncthreads();
    }
    if (tid == 0) out[g] = red[0] + bc[0];
}

extern "C" void kernel_launch(void* const* d_in, const int* in_sizes, int n_in,
                              void* d_out, int out_size, void* d_ws, size_t ws_size,
                              hipStream_t stream) {
    const int N = NNODES, E = NEDGES, G = NGRAPH;

    const float* x      = (const float*)d_in[0];
    const int*   ei     = (const int*)d_in[1];
    const int*   batch  = (const int*)d_in[2];
    const float* W1     = (const float*)d_in[3];
    const float* a1s    = (const float*)d_in[4];
    const float* a1d    = (const float*)d_in[5];
    const float* b1     = (const float*)d_in[6];
    const float* g1     = (const float*)d_in[7];
    const float* be1    = (const float*)d_in[8];
    const float* W2     = (const float*)d_in[9];
    const float* a2s    = (const float*)d_in[10];
    const float* a2d    = (const float*)d_in[11];
    const float* b2     = (const float*)d_in[12];
    const float* g2     = (const float*)d_in[13];
    const float* be2    = (const float*)d_in[14];
    const float* Wl     = (const float*)d_in[15];
    const float* bl     = (const float*)d_in[16];
    const float* Wc     = (const float*)d_in[17];
    const float* bc     = (const float*)d_in[18];

    // ---- workspace carve-up ----
    char* w = (char*)d_ws;
    void* h1    = (void*)w;  w += (size_t)N * 128 * 2;    // fp8: N*128B; fp16 h2 aliases
    float* acc1 = (float*)w; w += (size_t)N * 128 * 4;
    float* S    = (float*)w; w += (size_t)N * 4;
    float* Dv   = (float*)w; w += (size_t)N * 4;
    int* cnt    = (int*)w;   w += (size_t)N * 4;
    unsigned short* ssrc = (unsigned short*)w; w += (size_t)N * CAP * 2;
    float* Wt1  = (float*)w; w += (size_t)128 * 128 * 4;
    float* Wt2  = (float*)w; w += (size_t)128 * 64 * 4;
    float* sums = (float*)w; w += (size_t)G * 64 * 4;
    void* h2 = h1;

    const int TB = 256;
    const int gridN = (N + 255) / 256;

    // ---- prep (zero cnt/sums + W transposes) ----
    prep<<<gridN, 256, 0, stream>>>(W1, W2, Wt1, Wt2, cnt, sums);

    // ---- edge binning (random edges only; self-loops analytic) ----
    bin_edges<<<(E + TB - 1) / TB, TB, 0, stream>>>(ei, E, cnt, ssrc);

    // ---- layer 1 (128 -> 128), H in software-fp8: 1 LLC line per row gather ----
    gemm_scores<128, 128, 8, 1><<<N / 64, 256, 0, stream>>>(
        x, Wt1, a1s, a1d, h1, S, Dv);
    gat_aggr<128, 0, 1><<<N / 4, 256, 0, stream>>>(
        cnt, ssrc, S, Dv, h1, b1, g1, be1, acc1, nullptr, nullptr);

    // ---- layer 2 (128 -> 64), H in fp16 (row already 1 line), pool fused ----
    gemm_scores<128, 64, 4, 0><<<N / 64, 256, 0, stream>>>(
        acc1, Wt2, a2s, a2d, h2, S, Dv);
    gat_aggr<64, 1, 0><<<N / 4, 256, 0, stream>>>(
        cnt, ssrc, S, Dv, h2, b2, g2, be2, nullptr, batch, sums);

    // ---- head ----
    final_head<<<G, 64, 0, stream>>>(sums, batch, Wl, bl, Wc, bc, (float*)d_out);
}

// Round 18
// 272.332 us; speedup vs baseline: 1.0179x; 1.0179x over previous
//
#include <hip/hip_runtime.h>
#include <hip/hip_fp16.h>
#include <math.h>

#define NNODES 40000
#define NEDGES 640000
#define NGRAPH 64
#define CAP 96                 // slots per dst bucket (max random-degree ~45)
constexpr float LN_EPS = 1e-5f;

// ================= butterfly wave reduction (all lanes get result) =================
__device__ __forceinline__ float bf_sum(float v) {
    #pragma unroll
    for (int o = 32; o > 0; o >>= 1) v += __shfl_xor(v, o);
    return v;
}

// ================= prep: zero cnt/sums + transpose W1,W2 (one kernel) =================
__global__ void prep(const float* __restrict__ W1, const float* __restrict__ W2,
                     float* __restrict__ Wt1, float* __restrict__ Wt2,
                     int* __restrict__ cnt, float* __restrict__ sums) {
    int t = blockIdx.x * 256 + threadIdx.x;
    if (t < NNODES) cnt[t] = 0;
    if (t < 128 * 128) { int o = t / 128, i = t % 128; Wt1[i * 128 + o] = W1[t]; }
    if (t < 64 * 128)  { int o = t / 128, i = t % 128; Wt2[i * 64 + o] = W2[t]; }
    if (t < NGRAPH * 64) sums[t] = 0.f;
}

// ================= binning (random edges only; self-loops analytic) =================
__global__ void bin_edges(const int* __restrict__ ei, int E,
                          int* __restrict__ cnt, unsigned short* __restrict__ ssrc) {
    int e = blockIdx.x * blockDim.x + threadIdx.x;
    if (e >= E) return;
    int s = ei[e], d = ei[E + e];
    int pos = atomicAdd(cnt + d, 1);
    if (pos < CAP) ssrc[d * CAP + pos] = (unsigned short)s;
}

// ================= GEMM + scores: register-tiled 4ch x NPT nodes per thread =========
template<int DIN, int DOUT, int NPT>
__global__ __launch_bounds__(256) void gemm_scores(
        const float* __restrict__ X, const float* __restrict__ Wt,
        const float* __restrict__ asrc, const float* __restrict__ adst,
        __half* __restrict__ H, float* __restrict__ S, float* __restrict__ Dv) {
    constexpr int CHG = DOUT / 4;        // threads along channel dim
    constexpr int NG  = 256 / CHG;       // node-groups per block
    constexpr int NPB = NG * NPT;        // nodes per block
    static_assert(NPB == 64, "NPB must be 64");
    __shared__ float xs[DIN][NPB];
    __shared__ float ps[NG][NPT][2];
    const int base = blockIdx.x * NPB;
    const int tid = threadIdx.x;
    #pragma unroll
    for (int i4 = tid; i4 < NPB * DIN / 4; i4 += 256) {
        const int nd = i4 % NPB, c4 = i4 / NPB;
        float4 v = *(const float4*)(X + (size_t)(base + nd) * DIN + 4 * c4);
        xs[4 * c4 + 0][nd] = v.x;
        xs[4 * c4 + 1][nd] = v.y;
        xs[4 * c4 + 2][nd] = v.z;
        xs[4 * c4 + 3][nd] = v.w;
    }
    __syncthreads();
    const int cg = tid % CHG, ng = tid / CHG;
    const int c0 = 4 * cg, n0 = ng * NPT;
    float acc[NPT][4];
    #pragma unroll
    for (int n = 0; n < NPT; ++n)
        #pragma unroll
        for (int k = 0; k < 4; ++k) acc[n][k] = 0.f;
    #pragma unroll 2
    for (int i = 0; i < DIN; ++i) {
        const float4 w = *(const float4*)(Wt + i * DOUT + c0);
        #pragma unroll
        for (int n4 = 0; n4 < NPT / 4; ++n4) {
            const float4 xv = *(const float4*)&xs[i][n0 + 4 * n4];
            const float xf[4] = {xv.x, xv.y, xv.z, xv.w};
            #pragma unroll
            for (int j = 0; j < 4; ++j) {
                const int n = 4 * n4 + j;
                acc[n][0] += xf[j] * w.x; acc[n][1] += xf[j] * w.y;
                acc[n][2] += xf[j] * w.z; acc[n][3] += xf[j] * w.w;
            }
        }
    }
    #pragma unroll
    for (int n = 0; n < NPT; ++n) {
        __half2 p01 = __floats2half2_rn(acc[n][0], acc[n][1]);
        __half2 p23 = __floats2half2_rn(acc[n][2], acc[n][3]);
        __half2* hp = (__half2*)(H + (size_t)(base + n0 + n) * DOUT + c0);
        hp[0] = p01; hp[1] = p23;
    }
    const float4 asf = *(const float4*)(asrc + c0);
    const float4 adf = *(const float4*)(adst + c0);
    float sp[NPT], dp[NPT];
    #pragma unroll
    for (int n = 0; n < NPT; ++n) {
        sp[n] = acc[n][0]*asf.x + acc[n][1]*asf.y + acc[n][2]*asf.z + acc[n][3]*asf.w;
        dp[n] = acc[n][0]*adf.x + acc[n][1]*adf.y + acc[n][2]*adf.z + acc[n][3]*adf.w;
    }
    #pragma unroll
    for (int o = CHG / 2; o > 0; o >>= 1) {
        #pragma unroll
        for (int n = 0; n < NPT; ++n) {
            sp[n] += __shfl_xor(sp[n], o);
            dp[n] += __shfl_xor(dp[n], o);
        }
    }
    if (cg == 0) {
        #pragma unroll
        for (int n = 0; n < NPT; ++n) { ps[ng][n][0] = sp[n]; ps[ng][n][1] = dp[n]; }
    }
    __syncthreads();
    if (tid < NPB) {
        S[base + tid]  = ps[tid / NPT][tid % NPT][0];
        Dv[base + tid] = ps[tid / NPT][tid % NPT][1];
    }
}

// ================= fused GAT: 1 node/wave, unroll 8, two-readlane hot loop ==========
// 40000 waves maximize outstanding scattered loads. The wall is scattered-REQUEST
// service throughput (R6+R17: byte/line cuts gave <=6%), which is algorithmically
// fixed at 1 S-load + 1 H-row load per edge — this kernel sits on that roofline.
template<int D, int POOL>
__global__ __launch_bounds__(256) void gat_aggr(
        const int* __restrict__ cnt, const unsigned short* __restrict__ ssrc,
        const float* __restrict__ S, const float* __restrict__ Dv,
        const __half* __restrict__ H,
        const float* __restrict__ b, const float* __restrict__ gam,
        const float* __restrict__ bet,
        float* __restrict__ out, const int* __restrict__ batch,
        float* __restrict__ sums) {
    constexpr int VPL = D / 64;
    const int lane = threadIdx.x & 63;
    const int node = blockIdx.x * 4 + (threadIdx.x >> 6);   // 1 node per wave
    const int deg = min(__builtin_amdgcn_readfirstlane(cnt[node]), CAP);
    const float dsc = Dv[node];
    float ts = S[node] + dsc;
    ts = ts > 0.f ? ts : 0.2f * ts;
    const float aself = __expf(ts);                 // analytic self-loop term

    float z, acc0 = 0.f, acc1 = 0.f;

    if (deg <= 64) {
        // ---- phase 1: gather scores (zero-fill idle lanes) ----
        int s = 0; float a = 0.f;
        if (lane < deg) {
            s = ssrc[node * CAP + lane];
            float t = S[s] + dsc;
            t = t > 0.f ? t : 0.2f * t;
            a = __expf(t);
        }
        z = bf_sum(a);
        const int ab = __float_as_int(a);
        // ---- phase 2: aggregation, 8 loads in flight ----
        const int nmax = (deg + 7) & ~7;            // <= 64
        for (int j = 0; j < nmax; j += 8) {
            float af[8]; __half2 hv[8]; __half hs[8];
            #pragma unroll
            for (int u = 0; u < 8; ++u) {
                const int sj = __builtin_amdgcn_readlane(s, j + u);
                af[u] = __int_as_float(__builtin_amdgcn_readlane(ab, j + u));
                const __half* hp = H + (size_t)sj * D;
                if (VPL == 1) hs[u] = hp[lane];
                else          hv[u] = *(const __half2*)(hp + 2 * lane);
            }
            #pragma unroll
            for (int u = 0; u < 8; ++u) {
                if (VPL == 1) {
                    acc0 += af[u] * __half2float(hs[u]);
                } else {
                    acc0 += af[u] * __half2float(__low2half(hv[u]));
                    acc1 += af[u] * __half2float(__high2half(hv[u]));
                }
            }
        }
    } else {
        // ---- rare fallback: chunked loop (bucket deg > 64) ----
        float zz = 0.f;
        const int r0 = node * CAP;
        for (int bse = 0; bse < deg; bse += 64) {
            const int n = min(64, deg - bse);
            int s = 0; float a = 0.f;
            if (lane < n) {
                s = ssrc[r0 + bse + lane];
                float t = S[s] + dsc;
                t = t > 0.f ? t : 0.2f * t;
                a = __expf(t);
            }
            zz += bf_sum(a);
            const int abits = __float_as_int(a);
            for (int j = 0; j < n; ++j) {
                const int sj = __builtin_amdgcn_readlane(s, j);
                const float aj = __int_as_float(__builtin_amdgcn_readlane(abits, j));
                const __half* hp = H + (size_t)sj * D;
                if (VPL == 1) {
                    acc0 += aj * __half2float(hp[lane]);
                } else {
                    const float2 f = __half22float2(*(const __half2*)(hp + 2 * lane));
                    acc0 += aj * f.x; acc1 += aj * f.y;
                }
            }
        }
        z = zz;
    }

    // ---- self-loop contribution (coalesced row load) + z completion ----
    {
        const __half* hp = H + (size_t)node * D;
        if (VPL == 1) {
            acc0 += aself * __half2float(hp[lane]);
        } else {
            const float2 f = __half22float2(*(const __half2*)(hp + 2 * lane));
            acc0 += aself * f.x; acc1 += aself * f.y;
        }
        z += aself;
    }

    // ---- normalize + bias + ReLU + LayerNorm, intra-wave ----
    const float zinv = 1.0f / z;
    float vv[VPL], lsum = 0.f;
    vv[0] = acc0;
    if (VPL == 2) vv[1] = acc1;
    #pragma unroll
    for (int k = 0; k < VPL; ++k) {
        const int ch = VPL * lane + k;
        vv[k] = fmaxf(vv[k] * zinv + b[ch], 0.f);
        lsum += vv[k];
    }
    const float mu = bf_sum(lsum) / D;
    float q = 0.f;
    #pragma unroll
    for (int k = 0; k < VPL; ++k) { vv[k] -= mu; q += vv[k] * vv[k]; }
    const float rstd = rsqrtf(bf_sum(q) / D + LN_EPS);
    #pragma unroll
    for (int k = 0; k < VPL; ++k) {
        const int ch = VPL * lane + k;
        vv[k] = gam[ch] * vv[k] * rstd + bet[ch];
    }
    if (POOL) {
        const int bg = batch[node];                 // uniform per wave
        atomicAdd(&sums[bg * D + lane], vv[0]);     // POOL only used with D=64
    } else {
        if (VPL == 1) out[(size_t)node * D + lane] = vv[0];
        else *(float2*)(out + (size_t)node * D + 2 * lane) = make_float2(vv[0], vv[1]);
    }
}

// ================= head: mean (cnt via binary search on sorted batch) + 2 linears ====
__global__ void final_head(const float* __restrict__ sums, const int* __restrict__ batch,
                           const float* __restrict__ Wl, const float* __restrict__ bl,
                           const float* __restrict__ Wc, const float* __restrict__ bc,
                           float* __restrict__ out) {
    __shared__ float p[64];
    __shared__ float red[64];
    const int g = blockIdx.x, tid = threadIdx.x;
    int lo = 0, hi = NNODES;
    while (lo < hi) { int mid = (lo + hi) >> 1; if (batch[mid] < g) lo = mid + 1; else hi = mid; }
    int lo2 = lo, hi2 = NNODES;
    while (lo2 < hi2) { int mid = (lo2 + hi2) >> 1; if (batch[mid] < g + 1) lo2 = mid + 1; else hi2 = mid; }
    const float cnt = (float)(lo2 - lo);
    p[tid] = sums[g * 64 + tid] / fmaxf(cnt, 1.0f);
    __syncthreads();
    float t = bl[tid];
    #pragma unroll 8
    for (int k = 0; k < 64; ++k) t += Wl[tid * 64 + k] * p[k];
    red[tid] = Wc[tid] * t;
    __syncthreads();
    for (int s = 32; s > 0; s >>= 1) {
        if (tid < s) red[tid] += red[tid + s];
        __syncthreads();
    }
    if (tid == 0) out[g] = red[0] + bc[0];
}

extern "C" void kernel_launch(void* const* d_in, const int* in_sizes, int n_in,
                              void* d_out, int out_size, void* d_ws, size_t ws_size,
                              hipStream_t stream) {
    const int N = NNODES, E = NEDGES, G = NGRAPH;

    const float* x      = (const float*)d_in[0];
    const int*   ei     = (const int*)d_in[1];
    const int*   batch  = (const int*)d_in[2];
    const float* W1     = (const float*)d_in[3];
    const float* a1s    = (const float*)d_in[4];
    const float* a1d    = (const float*)d_in[5];
    const float* b1     = (const float*)d_in[6];
    const float* g1     = (const float*)d_in[7];
    const float* be1    = (const float*)d_in[8];
    const float* W2     = (const float*)d_in[9];
    const float* a2s    = (const float*)d_in[10];
    const float* a2d    = (const float*)d_in[11];
    const float* b2     = (const float*)d_in[12];
    const float* g2     = (const float*)d_in[13];
    const float* be2    = (const float*)d_in[14];
    const float* Wl     = (const float*)d_in[15];
    const float* bl     = (const float*)d_in[16];
    const float* Wc     = (const float*)d_in[17];
    const float* bc     = (const float*)d_in[18];

    // ---- workspace carve-up ----
    char* w = (char*)d_ws;
    __half* h1  = (__half*)w; w += (size_t)N * 128 * 2;   // fp16 H
    float* acc1 = (float*)w; w += (size_t)N * 128 * 4;
    float* S    = (float*)w; w += (size_t)N * 4;
    float* Dv   = (float*)w; w += (size_t)N * 4;
    int* cnt    = (int*)w;   w += (size_t)N * 4;
    unsigned short* ssrc = (unsigned short*)w; w += (size_t)N * CAP * 2;
    float* Wt1  = (float*)w; w += (size_t)128 * 128 * 4;
    float* Wt2  = (float*)w; w += (size_t)128 * 64 * 4;
    float* sums = (float*)w; w += (size_t)G * 64 * 4;
    __half* h2 = h1;

    const int TB = 256;
    const int gridN = (N + 255) / 256;

    // ---- prep (zero cnt/sums + W transposes) ----
    prep<<<gridN, 256, 0, stream>>>(W1, W2, Wt1, Wt2, cnt, sums);

    // ---- edge binning (random edges only; self-loops analytic) ----
    bin_edges<<<(E + TB - 1) / TB, TB, 0, stream>>>(ei, E, cnt, ssrc);

    // ---- layer 1 (128 -> 128) ----
    gemm_scores<128, 128, 8><<<N / 64, 256, 0, stream>>>(x, Wt1, a1s, a1d, h1, S, Dv);
    gat_aggr<128, 0><<<N / 4, 256, 0, stream>>>(cnt, ssrc, S, Dv, h1, b1, g1, be1,
                                                acc1, nullptr, nullptr);

    // ---- layer 2 (128 -> 64), pool fused ----
    gemm_scores<128, 64, 4><<<N / 64, 256, 0, stream>>>(acc1, Wt2, a2s, a2d, h2, S, Dv);
    gat_aggr<64, 1><<<N / 4, 256, 0, stream>>>(cnt, ssrc, S, Dv, h2, b2, g2, be2,
                                               nullptr, batch, sums);

    // ---- head ----
    final_head<<<G, 64, 0, stream>>>(sums, batch, Wl, bl, Wc, bc, (float*)d_out);
}